// Round 1
// baseline (3525.204 us; speedup 1.0000x reference)
//
#include <hip/hip_runtime.h>
#include <math.h>

#define DIM_ 2048
#define KTOP 8
#define NPAIR 28
#define MSLOT 16
#define TSTEPS 256
#define NB 64
#define NTHREADS 256
#define EPT 8

static_assert(NTHREADS * EPT == DIM_, "mapping");

__device__ __forceinline__ void argmax64(float &bv, int &bi) {
#pragma unroll
  for (int off = 32; off >= 1; off >>= 1) {
    float ov = __shfl_xor(bv, off, 64);
    int oi = __shfl_xor(bi, off, 64);
    bool take = (ov > bv) || (ov == bv && oi < bi);
    bv = take ? ov : bv;
    bi = take ? oi : bi;
  }
}

__global__ void __launch_bounds__(NTHREADS)
me_fused(const float *__restrict__ x, const float *__restrict__ tape_re,
         const float *__restrict__ tape_im, const float *__restrict__ eta_param,
         const float *__restrict__ tbias_re, const float *__restrict__ tbias_im,
         float *__restrict__ out) {
  __shared__ float s_re[DIM_], s_im[DIM_];
  __shared__ float h_sh[DIM_];
  __shared__ float d_re[DIM_], d_im[DIM_];
  __shared__ float cand_v[32];
  __shared__ int cand_i[32];
  __shared__ int topidx[KTOP];
  __shared__ int sl_ti[MSLOT], sl_tj[MSLOT], sl_cnt[MSLOT];
  __shared__ float sl_mre[MSLOT], sl_mim[MSLOT];
  __shared__ float red_sh[NTHREADS / 64];

  const int tid = threadIdx.x;
  const int lane = tid & 63;
  const int wid = tid >> 6;
  const int b = blockIdx.x;

  if (tid < MSLOT) {
    sl_ti[tid] = 0; sl_tj[tid] = 0; sl_cnt[tid] = 0;
    sl_mre[tid] = 0.f; sl_mim[tid] = 0.f;
  }

  const float eta = fabsf(eta_param[0]);

  float sre[EPT], sim[EPT], tbre[EPT], tbim[EPT];
  float acc = 0.f;
#pragma unroll
  for (int j = 0; j < EPT; j++) {
    int d = tid + NTHREADS * j;
    float a = tape_re[d], c2 = tape_im[d];
    sre[j] = a; sim[j] = c2;
    tbre[j] = tbias_re[d]; tbim[j] = tbias_im[d];
    acc += a * a + c2 * c2;
  }
#pragma unroll
  for (int off = 32; off >= 1; off >>= 1) acc += __shfl_xor(acc, off, 64);
  if (lane == 0) red_sh[wid] = acc;
  __syncthreads();
  float tot = 0.f;
#pragma unroll
  for (int w = 0; w < NTHREADS / 64; w++) tot += red_sh[w];
  float inv0 = 1.f / fmaxf(sqrtf(tot), 1e-8f);
#pragma unroll
  for (int j = 0; j < EPT; j++) {
    int d = tid + NTHREADS * j;
    sre[j] *= inv0; sim[j] *= inv0;
    s_re[d] = sre[j]; s_im[d] = sim[j];
  }

  const float *xb = x + (size_t)b * TSTEPS * DIM_;
  float hcur[EPT], hnext[EPT];
#pragma unroll
  for (int j = 0; j < EPT; j++) hcur[j] = xb[tid + NTHREADS * j];
#pragma unroll
  for (int j = 0; j < EPT; j++) hnext[j] = hcur[j];

  __syncthreads();

  for (int t = 0; t < TSTEPS; t++) {
    // ---- phase 1: c = h*s, stage h, zero deltas ----
    float kv[EPT]; int kd[EPT];
#pragma unroll
    for (int j = 0; j < EPT; j++) {
      int d = tid + NTHREADS * j;
      float h = hcur[j];
      h_sh[d] = h;
      d_re[d] = 0.f; d_im[d] = 0.f;
      float cr = h * sre[j], ci2 = h * sim[j];
      kv[j] = sqrtf(cr * cr + ci2 * ci2); // sort key = |c| (matches ref abs)
      kd[j] = d;
    }
    if (t + 1 < TSTEPS) {
      const float *xr = xb + (size_t)(t + 1) * DIM_;
#pragma unroll
      for (int j = 0; j < EPT; j++) hnext[j] = xr[tid + NTHREADS * j];
    }

    // ---- phase 2a: per-wave top-8 (8 argmax extraction rounds) ----
#pragma unroll
    for (int r = 0; r < KTOP; r++) {
      float bv = kv[0]; int bi = kd[0];
#pragma unroll
      for (int j = 1; j < EPT; j++) {
        bool take = (kv[j] > bv); // ascending j => lower idx kept on tie
        bv = take ? kv[j] : bv;
        bi = take ? kd[j] : bi;
      }
      argmax64(bv, bi);
      if (lane == 0) { cand_v[wid * KTOP + r] = bv; cand_i[wid * KTOP + r] = bi; }
#pragma unroll
      for (int j = 0; j < EPT; j++)
        if (kd[j] == bi) kv[j] = -__builtin_inff();
    }
    __syncthreads(); // B1

    // ---- phase 2b-e: wave 0 serial section ----
    if (wid == 0) {
      float cv = (lane < 4 * KTOP) ? cand_v[lane] : -__builtin_inff();
      int cidx = (lane < 4 * KTOP) ? cand_i[lane] : 0x7fffffff;
#pragma unroll
      for (int r = 0; r < KTOP; r++) {
        float bv = cv; int bi = cidx;
        argmax64(bv, bi);
        if (lane == 0) topidx[r] = bi;
        if (cidx == bi) cv = -__builtin_inff();
      }
      __builtin_amdgcn_wave_barrier();

      // pair (ii,jj) for lane p (row-major triu order)
      int p = lane;
      int ii = 0, jj = 1;
      {
        int pp = (p < NPAIR) ? p : 0;
        int i = 0;
        while (i < 7 && pp >= 7 - i) { pp -= 7 - i; i++; }
        ii = i; jj = i + 1 + pp;
      }
      float score = 0.f; bool pos = false;
      int gi = 0, gj = 0;
      float pre = 0.f, pim = 0.f;
      if (p < NPAIR) {
        gi = topidx[ii]; gj = topidx[jj];
        float hi = h_sh[gi], hj = h_sh[gj];
        float sri = s_re[gi], sii = s_im[gi];
        float srj = s_re[gj], sij = s_im[gj];
        float cri = hi * sri, cii = hi * sii;
        float crj = hj * srj, cij = hj * sij;
        score = cri * crj + cii * cij; // Re(c_i * conj(c_j))
        pos = score > 0.f;
        float pr = sri * srj - sii * sij;
        float pq = sri * sij + sii * srj;
        float ap = fmaxf(sqrtf(pr * pr + pq * pq), 1e-8f);
        pre = (0.05f * pr) / ap;
        pim = (0.05f * pq) / ap;
      }
      unsigned long long posmask = __ballot(pos);
      int npos = __popcll(posmask);
      int nbind = (int)((float)npos * 0.15f);
      if (nbind < 1) nbind = 1;
      int npm1 = npos - 1; if (npm1 < 0) npm1 = 0;
      int thidx = (nbind - 1 < npm1) ? (nbind - 1) : npm1;
      int g = 0;
      for (int q = 0; q < NPAIR; q++) {
        float sq = __shfl(score, q, 64);
        if (((posmask >> q) & 1ull) && sq > score) g++;
      }
      float candt = (pos && g <= thidx) ? score : __builtin_inff();
#pragma unroll
      for (int off = 32; off >= 1; off >>= 1)
        candt = fminf(candt, __shfl_xor(candt, off, 64));
      bool bind = (npos > 0) && (p < NPAIR) && (score >= candt);
      unsigned long long bmask = __ballot(bind);

      // slot scan: lanes 0..15 own slots; iterate bound pairs in order
      int myti = 0, mytj = 0, mycnt = 0;
      float mymre = 0.f, mymim = 0.f;
      if (lane < MSLOT) {
        myti = sl_ti[lane]; mytj = sl_tj[lane]; mycnt = sl_cnt[lane];
        mymre = sl_mre[lane]; mymim = sl_mim[lane];
      }
      while (bmask) {
        int pp = __ffsll(bmask) - 1;
        bmask &= bmask - 1;
        int pci = __shfl(gi, pp, 64);
        int pcj = __shfl(gj, pp, 64);
        float pmr = __shfl(pre, pp, 64);
        float pmi = __shfl(pim, pp, 64);
        bool active = (lane < MSLOT) && (mycnt > 0);
        bool match = active && ((myti == pci && mytj == pcj) ||
                                (myti == pcj && mytj == pci));
        unsigned long long mm = __ballot(match);
        bool freeslot = (lane < MSLOT) && (mycnt <= 0);
        unsigned long long fm = __ballot(freeslot);
        if (mm != 0ull) {
          int midx = __ffsll(mm) - 1;
          if (lane == midx) mycnt = 5; // refresh lifetime only
        } else if (fm != 0ull) {
          int fidx = __ffsll(fm) - 1;
          if (lane == fidx) {
            myti = pci; mytj = pcj; mymre = pmr; mymim = pmi; mycnt = 5;
          }
        }
      }
      if (lane < MSLOT) {
        mymre *= 0.9f; mymim *= 0.9f; mycnt -= 1;
        bool alive = (mycnt > 0) &&
                     (sqrtf(mymre * mymre + mymim * mymim) > 1e-6f);
        if (!alive) { mycnt = 0; mymre = 0.f; mymim = 0.f; }
        sl_ti[lane] = myti; sl_tj[lane] = mytj; sl_cnt[lane] = mycnt;
        sl_mre[lane] = mymre; sl_mim[lane] = mymim;
        atomicAdd(&d_re[myti], 0.1f * mymre);
        atomicAdd(&d_re[mytj], 0.1f * mymre);
        atomicAdd(&d_im[myti], 0.1f * mymim);
        atomicAdd(&d_im[mytj], 0.1f * mymim);
      }
    }
    __syncthreads(); // B2

    // ---- phase 3: masked update + renorm + output ----
    float tre[EPT], tim[EPT];
    float acc2 = 0.f;
#pragma unroll
    for (int j = 0; j < EPT; j++) {
      int d = tid + NTHREADS * j;
      float ar = sre[j] + d_re[d];
      float ai = sim[j] + d_im[d];
      float h = hcur[j];
      float car = h * ar, cai = h * ai;
      bool res = (car > 1e-6f) && (fabsf(cai) < car);
      bool tor = (car < -1e-6f) || (fabsf(cai) >= fabsf(car));
      float m1 = (res || tor) ? 1.f : 0.f; // 1 - orth_mask
      float mt = tor ? 1.f : 0.f;
      float ur = eta * (car * m1 + mt * tbre[j]);
      float ui = eta * (cai * m1 + mt * tbim[j]);
      tre[j] = sre[j] + ur;
      tim[j] = sim[j] + ui;
      acc2 += tre[j] * tre[j] + tim[j] * tim[j];
    }
#pragma unroll
    for (int off = 32; off >= 1; off >>= 1) acc2 += __shfl_xor(acc2, off, 64);
    if (lane == 0) red_sh[wid] = acc2;
    __syncthreads(); // Bred
    float tot2 = 0.f;
#pragma unroll
    for (int w = 0; w < NTHREADS / 64; w++) tot2 += red_sh[w];
    float invn = 1.f / fmaxf(sqrtf(tot2), 1e-8f);
    float *orow = out + ((size_t)b * TSTEPS + t) * DIM_;
#pragma unroll
    for (int j = 0; j < EPT; j++) {
      int d = tid + NTHREADS * j;
      float nr = tre[j] * invn, ni = tim[j] * invn;
      sre[j] = nr; sim[j] = ni;
      s_re[d] = nr; s_im[d] = ni;
      orow[d] = sqrtf(nr * nr + ni * ni);
    }
#pragma unroll
    for (int j = 0; j < EPT; j++) hcur[j] = hnext[j];
  }
}

extern "C" void kernel_launch(void *const *d_in, const int *in_sizes, int n_in,
                              void *d_out, int out_size, void *d_ws,
                              size_t ws_size, hipStream_t stream) {
  const float *x = (const float *)d_in[0];
  const float *tre = (const float *)d_in[1];
  const float *tim = (const float *)d_in[2];
  const float *eta = (const float *)d_in[3];
  const float *tbre = (const float *)d_in[4];
  const float *tbim = (const float *)d_in[5];
  float *out = (float *)d_out;
  me_fused<<<NB, NTHREADS, 0, stream>>>(x, tre, tim, eta, tbre, tbim, out);
}

// Round 2
// 1378.941 us; speedup vs baseline: 2.5565x; 2.5565x over previous
//
#include <hip/hip_runtime.h>
#include <math.h>

#define DIM_ 2048
#define KTOP 8
#define MSLOT 16
#define TSTEPS 256
#define NB 64
#define NTHREADS 256
#define EPT 8
#define NWAVE (NTHREADS / 64)

static_assert(NTHREADS * EPT == DIM_, "mapping");

// ---- DPP helpers (VALU-pipe cross-lane, no LDS latency) ----
// update_dpp(old=0, bound_ctrl=1): invalid/masked-out source lanes produce 0,
// which is the identity for (a) max of non-negative keys, (b) f32 sum,
// (c) f32 max guarded by npos>0 (real max is > 0).
#define DPP0(src, ctrl, rm) __builtin_amdgcn_update_dpp(0, (src), (ctrl), (rm), 0xf, true)

#define DMAX_STAGE(x, ctrl, rm)                                                \
  do {                                                                         \
    int _lo = DPP0(__double2loint(x), ctrl, rm);                               \
    int _hi = DPP0(__double2hiint(x), ctrl, rm);                               \
    x = fmax(x, __hiloint2double(_hi, _lo));                                   \
  } while (0)

__device__ __forceinline__ double wave_max_f64(double x) {
  DMAX_STAGE(x, 0x111, 0xf); // row_shr:1
  DMAX_STAGE(x, 0x112, 0xf); // row_shr:2
  DMAX_STAGE(x, 0x114, 0xf); // row_shr:4
  DMAX_STAGE(x, 0x118, 0xf); // row_shr:8
  DMAX_STAGE(x, 0x142, 0xa); // row_bcast15 -> rows 1,3
  DMAX_STAGE(x, 0x143, 0xc); // row_bcast31 -> rows 2,3
  return x; // lane 63 holds the wave max
}

#define FMAX_STAGE(x, ctrl, rm)                                                \
  x = fmaxf(x, __int_as_float(DPP0(__float_as_int(x), ctrl, rm)))
#define FADD_STAGE(x, ctrl, rm)                                                \
  x = x + __int_as_float(DPP0(__float_as_int(x), ctrl, rm))

__device__ __forceinline__ float wave_max_f32(float x) {
  FMAX_STAGE(x, 0x111, 0xf);
  FMAX_STAGE(x, 0x112, 0xf);
  FMAX_STAGE(x, 0x114, 0xf);
  FMAX_STAGE(x, 0x118, 0xf);
  FMAX_STAGE(x, 0x142, 0xa);
  FMAX_STAGE(x, 0x143, 0xc);
  return x;
}
__device__ __forceinline__ float wave_sum_f32(float x) {
  FADD_STAGE(x, 0x111, 0xf);
  FADD_STAGE(x, 0x112, 0xf);
  FADD_STAGE(x, 0x114, 0xf);
  FADD_STAGE(x, 0x118, 0xf);
  FADD_STAGE(x, 0x142, 0xa);
  FADD_STAGE(x, 0x143, 0xc);
  return x;
}

__device__ __forceinline__ int rl63(int v) {
  return __builtin_amdgcn_readlane(v, 63);
}

__global__ void __launch_bounds__(NTHREADS)
me_fused(const float *__restrict__ x, const float *__restrict__ tape_re,
         const float *__restrict__ tape_im, const float *__restrict__ eta_param,
         const float *__restrict__ tbias_re, const float *__restrict__ tbias_im,
         float *__restrict__ out) {
  __shared__ float4 sc4[DIM_];                     // (h, vre, vim, 0)
  __shared__ float dre_s[DIM_], dim_s[DIM_];       // transient scatter deltas
  __shared__ unsigned long long cand_lds[NWAVE * KTOP];
  __shared__ float red_sh[2][NWAVE];               // norm^2 partials, dbuf

  const int tid = threadIdx.x;
  const int lane = tid & 63;
  const int wid = tid >> 6;
  const int b = blockIdx.x;

  const float eta = fabsf(eta_param[0]);

  // state: UNNORMALIZED s (= previous step's t-vector); ivn applied per step
  float vre[EPT], vim[EPT], tbre_[EPT], tbim_[EPT];
  float acc = 0.f;
#pragma unroll
  for (int j = 0; j < EPT; j++) {
    int d = tid + NTHREADS * j;
    float a = tape_re[d], c2 = tape_im[d];
    vre[j] = a; vim[j] = c2;
    tbre_[j] = tbias_re[d]; tbim_[j] = tbias_im[d];
    acc += a * a + c2 * c2;
  }
  {
    float ws = wave_sum_f32(acc);
    int wtot = rl63(__float_as_int(ws));
    if (lane == 0) red_sh[0][wid] = __int_as_float(wtot);
  }

  // transient slot state lives in wave0's registers (lanes 0..15 own slots)
  int s_ti = 0, s_tj = 0, s_cnt = 0;
  float s_mre = 0.f, s_mim = 0.f;

  const float *xb = x + (size_t)b * TSTEPS * DIM_;
  float hcur[EPT], hnext[EPT];
#pragma unroll
  for (int j = 0; j < EPT; j++) { hcur[j] = xb[tid + NTHREADS * j]; hnext[j] = hcur[j]; }

  __syncthreads();

  float ivn = 0.f;
  for (int t = 0; t < TSTEPS; t++) {
    // ================= [A] stage LDS + wave-local top-8 =================
    double key[EPT];
#pragma unroll
    for (int j = 0; j < EPT; j++) {
      int d = tid + NTHREADS * j;
      float h = hcur[j];
      float cr = h * vre[j], ci = h * vim[j];
      float av = sqrtf(cr * cr + ci * ci); // ordering key (scale-invariant)
      key[j] = __hiloint2double(__float_as_int(av), ~d); // unique, >0
      sc4[d] = make_float4(h, vre[j], vim[j], 0.f);
      dre_s[d] = 0.f; dim_s[d] = 0.f;
    }
    if (t + 1 < TSTEPS) {
      const float *xr = xb + (size_t)(t + 1) * DIM_;
#pragma unroll
      for (int j = 0; j < EPT; j++) hnext[j] = xr[tid + NTHREADS * j];
    }
    // wave-local sorted top-8 (keys unique -> strict threshold exclusion)
    {
      double cnd = fmax(fmax(fmax(key[0], key[1]), fmax(key[2], key[3])),
                        fmax(fmax(key[4], key[5]), fmax(key[6], key[7])));
#pragma unroll
      for (int r = 0; r < KTOP; r++) {
        double m = wave_max_f64(cnd);
        int hi_s = rl63(__double2hiint(m));
        int lo_s = rl63(__double2loint(m));
        if (lane == 0)
          cand_lds[wid * KTOP + r] =
              (((unsigned long long)(unsigned)hi_s) << 32) | (unsigned)lo_s;
        if (r < KTOP - 1) {
          double kth = __hiloint2double(hi_s, lo_s);
          double c2 = 0.0;
#pragma unroll
          for (int j = 0; j < EPT; j++)
            c2 = fmax(c2, key[j] < kth ? key[j] : 0.0);
          cnd = c2;
        }
      }
    }
    __syncthreads(); // B1

    // per-step scalar: ivn = 1/max(||v||,1e-8)  (broadcast reads)
    {
      int p = t & 1;
      float tot = red_sh[p][0] + red_sh[p][1] + red_sh[p][2] + red_sh[p][3];
      ivn = 1.f / fmaxf(sqrtf(tot), 1e-8f);
    }

    // ================= [B] wave0 serial section =================
    if (wid == 0) {
      // merge 32 wave candidates -> global sorted top-8
      double cnd2 = (lane < NWAVE * KTOP)
                        ? __longlong_as_double((long long)cand_lds[lane])
                        : 0.0;
      int top[KTOP];
#pragma unroll
      for (int r = 0; r < KTOP; r++) {
        double m = wave_max_f64(cnd2);
        int hi_s = rl63(__double2hiint(m));
        int lo_s = rl63(__double2loint(m));
        top[r] = ~lo_s; // recover index
        if (__double2loint(cnd2) == lo_s) cnd2 = 0.0; // purge (lo unique)
      }
      // pair (ii,jj) for lane p, row-major triu order
      int pi = (lane < 28) ? lane : 27;
      int ii = 0, base = 0;
      if (pi >= 7)  { ii = 1; base = 7;  }
      if (pi >= 13) { ii = 2; base = 13; }
      if (pi >= 18) { ii = 3; base = 18; }
      if (pi >= 22) { ii = 4; base = 22; }
      if (pi >= 25) { ii = 5; base = 25; }
      if (pi >= 27) { ii = 6; base = 27; }
      int jj = ii + 1 + (pi - base);
      int gi = top[0];
      if (ii == 1) gi = top[1];
      if (ii == 2) gi = top[2];
      if (ii == 3) gi = top[3];
      if (ii == 4) gi = top[4];
      if (ii == 5) gi = top[5];
      if (ii == 6) gi = top[6];
      int gj = top[1];
      if (jj == 2) gj = top[2];
      if (jj == 3) gj = top[3];
      if (jj == 4) gj = top[4];
      if (jj == 5) gj = top[5];
      if (jj == 6) gj = top[6];
      if (jj == 7) gj = top[7];

      float4 c4i = sc4[gi], c4j = sc4[gj];
      float sri = c4i.y * ivn, sii2 = c4i.z * ivn;
      float srj = c4j.y * ivn, sij = c4j.z * ivn;
      float cri = c4i.x * sri, cii = c4i.x * sii2;
      float crj = c4j.x * srj, cij = c4j.x * sij;
      float score = cri * crj + cii * cij; // Re(c_i conj(c_j))
      bool valid = (lane < 28);
      bool pos = valid && (score > 0.f);
      unsigned long long posmask = __ballot(pos);
      int npos = __popcll(posmask);
      // mnew (unit-phase, 0.05 magnitude)
      float pr = sri * srj - sii2 * sij;
      float pq = sri * sij + sii2 * srj;
      float ap = fmaxf(sqrtf(pr * pr + pq * pq), 1e-8f);
      float mr = (0.05f * pr) / ap, mi = (0.05f * pq) / ap;

      unsigned long long bmask = 0ull;
      if (npos > 0) {
        int nbind = (int)((float)npos * 0.15f);
        if (nbind < 1) nbind = 1;
        float val = pos ? score : -__builtin_inff();
        float th = 0.f;
        for (int k2 = 0; k2 < nbind; ++k2) {
          float mx = wave_max_f32(val);
          th = __int_as_float(rl63(__float_as_int(mx)));
          if (k2 + 1 < nbind) {
            unsigned long long em = __ballot(val == th);
            if (lane == (int)__builtin_ctzll(em)) val = -__builtin_inff();
          }
        }
        bool bind = valid && (score >= th);
        bmask = __ballot(bind);
      }
      // slot scan: process bound pairs in pair order (low lane first)
      while (bmask) {
        int pp = (int)__builtin_ctzll(bmask);
        bmask &= bmask - 1;
        int pci = __builtin_amdgcn_readlane(gi, pp);
        int pcj = __builtin_amdgcn_readlane(gj, pp);
        int pmr = __builtin_amdgcn_readlane(__float_as_int(mr), pp);
        int pmi = __builtin_amdgcn_readlane(__float_as_int(mi), pp);
        bool isslot = (lane < MSLOT);
        bool match = isslot && (s_cnt > 0) &&
                     ((s_ti == pci && s_tj == pcj) ||
                      (s_ti == pcj && s_tj == pci));
        unsigned long long mm = __ballot(match);
        if (mm != 0ull) {
          if (lane == (int)__builtin_ctzll(mm)) s_cnt = 5; // refresh only
        } else {
          unsigned long long fm = __ballot(isslot && s_cnt <= 0);
          if (fm != 0ull && lane == (int)__builtin_ctzll(fm)) {
            s_ti = pci; s_tj = pcj;
            s_mre = __int_as_float(pmr); s_mim = __int_as_float(pmi);
            s_cnt = 5;
          }
        }
      }
      // decay + alive + scatter (dead slots add exact 0.0, like the ref)
      if (lane < MSLOT) {
        s_mre *= 0.9f; s_mim *= 0.9f; s_cnt -= 1;
        bool alive = (s_cnt > 0) &&
                     (sqrtf(s_mre * s_mre + s_mim * s_mim) > 1e-6f);
        if (!alive) { s_cnt = 0; s_mre = 0.f; s_mim = 0.f; }
        atomicAdd(&dre_s[s_ti], 0.1f * s_mre);
        atomicAdd(&dre_s[s_tj], 0.1f * s_mre);
        atomicAdd(&dim_s[s_ti], 0.1f * s_mim);
        atomicAdd(&dim_s[s_tj], 0.1f * s_mim);
      }
    }
    __syncthreads(); // B2

    // ================= [D] update + deferred output =================
    if (t > 0) {
      float *op = out + ((size_t)b * TSTEPS + (t - 1)) * DIM_;
#pragma unroll
      for (int j = 0; j < EPT; j++) {
        int d = tid + NTHREADS * j;
        float sr = vre[j] * ivn, si = vim[j] * ivn;
        op[d] = sqrtf(sr * sr + si * si);
      }
    }
    float acc2 = 0.f;
#pragma unroll
    for (int j = 0; j < EPT; j++) {
      int d = tid + NTHREADS * j;
      float sri = vre[j] * ivn, sii2 = vim[j] * ivn; // normalized s
      float ar = sri + dre_s[d], ai = sii2 + dim_s[d];
      float h = hcur[j];
      float car = h * ar, cai = h * ai;
      bool res = (car > 1e-6f) && (fabsf(cai) < car);
      bool tor = (car < -1e-6f) || (fabsf(cai) >= fabsf(car));
      float m1 = (res || tor) ? 1.f : 0.f;
      float mt = tor ? 1.f : 0.f;
      float ur = eta * (car * m1 + mt * tbre_[j]);
      float ui = eta * (cai * m1 + mt * tbim_[j]);
      float nr = sri + ur, ni = sii2 + ui;
      acc2 += nr * nr + ni * ni;
      vre[j] = nr; vim[j] = ni; // new UNNORMALIZED state
    }
    {
      float ws = wave_sum_f32(acc2);
      int wtot = rl63(__float_as_int(ws));
      if (lane == 0) red_sh[(t & 1) ^ 1][wid] = __int_as_float(wtot);
    }
#pragma unroll
    for (int j = 0; j < EPT; j++) hcur[j] = hnext[j];
  }

  // epilogue: last output row
  __syncthreads();
  {
    float tot = red_sh[0][0] + red_sh[0][1] + red_sh[0][2] + red_sh[0][3];
    float ivnF = 1.f / fmaxf(sqrtf(tot), 1e-8f);
    float *op = out + ((size_t)b * TSTEPS + (TSTEPS - 1)) * DIM_;
#pragma unroll
    for (int j = 0; j < EPT; j++) {
      int d = tid + NTHREADS * j;
      float sr = vre[j] * ivnF, si = vim[j] * ivnF;
      op[d] = sqrtf(sr * sr + si * si);
    }
  }
}

extern "C" void kernel_launch(void *const *d_in, const int *in_sizes, int n_in,
                              void *d_out, int out_size, void *d_ws,
                              size_t ws_size, hipStream_t stream) {
  const float *x = (const float *)d_in[0];
  const float *tre = (const float *)d_in[1];
  const float *tim = (const float *)d_in[2];
  const float *eta = (const float *)d_in[3];
  const float *tbre = (const float *)d_in[4];
  const float *tbim = (const float *)d_in[5];
  float *out = (float *)d_out;
  me_fused<<<NB, NTHREADS, 0, stream>>>(x, tre, tim, eta, tbre, tbim, out);
}

// Round 3
// 1058.082 us; speedup vs baseline: 3.3317x; 1.3032x over previous
//
#include <hip/hip_runtime.h>
#include <math.h>

#define DIM_ 2048
#define KTOP 8
#define MSLOT 16
#define TSTEPS 256
#define NB 64
#define NTHREADS 320 // 5 waves: wave0 = serial wave, waves 1..4 = workers
#define NWORK 256
#define EPT 8

static_assert(NWORK * EPT == DIM_, "mapping");

#define DPP0(src, ctrl, rm) __builtin_amdgcn_update_dpp(0, (src), (ctrl), (rm), 0xf, true)

// ---- f64 packed-key helpers (key = f32bits(|c|) : ~index, never NaN) ----
__device__ __forceinline__ void ced(double &a, double &b) {
  double mx = fmax(a, b);
  b = fmin(a, b);
  a = mx;
}

// Batcher odd-even mergesort, 8 elements, descending (19 CE)
__device__ __forceinline__ void sort8_desc(double k[8]) {
  ced(k[0],k[1]); ced(k[2],k[3]); ced(k[4],k[5]); ced(k[6],k[7]);
  ced(k[0],k[2]); ced(k[1],k[3]); ced(k[4],k[6]); ced(k[5],k[7]);
  ced(k[1],k[2]); ced(k[5],k[6]);
  ced(k[0],k[4]); ced(k[1],k[5]); ced(k[2],k[6]); ced(k[3],k[7]);
  ced(k[2],k[4]); ced(k[3],k[5]);
  ced(k[1],k[2]); ced(k[3],k[4]); ced(k[5],k[6]);
}

// one merge-reduction level: pull partner's sorted-desc 8-list via DPP,
// half-clean (top-8 of union), bitonic resort to sorted-desc.
// bound_ctrl=1 zero-fill = identity (keys > 0).
template <int CTRL, int RM>
__device__ __forceinline__ void merge_level(double k[8]) {
  double b[8];
#pragma unroll
  for (int i = 0; i < 8; i++) {
    int lo = DPP0(__double2loint(k[i]), CTRL, RM);
    int hi = DPP0(__double2hiint(k[i]), CTRL, RM);
    b[i] = __hiloint2double(hi, lo);
  }
#pragma unroll
  for (int i = 0; i < 8; i++) k[i] = fmax(k[i], b[7 - i]);
  ced(k[0],k[4]); ced(k[1],k[5]); ced(k[2],k[6]); ced(k[3],k[7]);
  ced(k[0],k[2]); ced(k[1],k[3]); ced(k[4],k[6]); ced(k[5],k[7]);
  ced(k[0],k[1]); ced(k[2],k[3]); ced(k[4],k[5]); ced(k[6],k[7]);
}

#define FMAX_STAGE(x, ctrl, rm)                                                \
  x = fmaxf(x, __int_as_float(DPP0(__float_as_int(x), ctrl, rm)))
#define FADD_STAGE(x, ctrl, rm)                                                \
  x = x + __int_as_float(DPP0(__float_as_int(x), ctrl, rm))

__device__ __forceinline__ float wave_max_f32(float x) {
  FMAX_STAGE(x, 0x111, 0xf);
  FMAX_STAGE(x, 0x112, 0xf);
  FMAX_STAGE(x, 0x114, 0xf);
  FMAX_STAGE(x, 0x118, 0xf);
  FMAX_STAGE(x, 0x142, 0xa);
  FMAX_STAGE(x, 0x143, 0xc);
  return x; // lane 63 has the max
}
__device__ __forceinline__ float wave_sum_f32(float x) {
  FADD_STAGE(x, 0x111, 0xf);
  FADD_STAGE(x, 0x112, 0xf);
  FADD_STAGE(x, 0x114, 0xf);
  FADD_STAGE(x, 0x118, 0xf);
  FADD_STAGE(x, 0x142, 0xa);
  FADD_STAGE(x, 0x143, 0xc);
  return x; // lane 63 has the sum
}
__device__ __forceinline__ int rl63(int v) {
  return __builtin_amdgcn_readlane(v, 63);
}

__global__ void __launch_bounds__(NTHREADS)
me_fused(const float *__restrict__ x, const float *__restrict__ tape_re,
         const float *__restrict__ tape_im, const float *__restrict__ eta_param,
         const float *__restrict__ tbias_re, const float *__restrict__ tbias_im,
         float *__restrict__ out) {
  __shared__ float4 sc4[DIM_];                       // (h, vre, vim, 0)
  __shared__ float2 dxy[DIM_];                       // scatter deltas
  __shared__ unsigned long long cand_lds[4 * KTOP];  // 4 sorted wave lists
  __shared__ float red_sh[4];                        // norm^2 partials

  const int tid = threadIdx.x;
  const int lane = tid & 63;
  const int wid = tid >> 6;
  const int wtid = tid - 64; // worker element base (valid for wid>0)
  const int b = blockIdx.x;

  const float eta = fabsf(eta_param[0]);

  // worker state (unnormalized v; ivn applied per step)
  float vre[EPT], vim[EPT], tbre_[EPT], tbim_[EPT];
  float hcur[EPT], hnext[EPT];
  const float *xb = x + (size_t)b * TSTEPS * DIM_;

  if (wid > 0) {
    float acc = 0.f;
#pragma unroll
    for (int j = 0; j < EPT; j++) {
      int e = wtid + NWORK * j;
      float a = tape_re[e], c2 = tape_im[e];
      vre[j] = a; vim[j] = c2;
      tbre_[j] = tbias_re[e]; tbim_[j] = tbias_im[e];
      hcur[j] = xb[e]; hnext[j] = hcur[j];
      acc += a * a + c2 * c2;
    }
    float ws = wave_sum_f32(acc);
    if (lane == 63) red_sh[wid - 1] = ws;
  }

  // transient slots live in wave0 registers (lanes 0..15)
  int s_ti = 0, s_tj = 0, s_cnt = 0;
  float s_mre = 0.f, s_mim = 0.f;

  __syncthreads();

  for (int t = 0; t < TSTEPS; t++) {
    // ============ [A] workers: stage LDS + sorted top-8 ============
    if (wid > 0) {
      double key[EPT];
#pragma unroll
      for (int j = 0; j < EPT; j++) {
        int e = wtid + NWORK * j;
        float h = hcur[j];
        float cr = h * vre[j], ci = h * vim[j];
        float av = sqrtf(cr * cr + ci * ci); // scale-invariant ordering key
        key[j] = __hiloint2double(__float_as_int(av), ~e); // unique, > 0
        sc4[e] = make_float4(h, vre[j], vim[j], 0.f);
        dxy[e] = make_float2(0.f, 0.f);
      }
      sort8_desc(key);
      merge_level<0x111, 0xf>(key); // row_shr:1
      merge_level<0x112, 0xf>(key); // row_shr:2
      merge_level<0x114, 0xf>(key); // row_shr:4
      merge_level<0x118, 0xf>(key); // row_shr:8
      merge_level<0x142, 0xa>(key); // row_bcast15
      merge_level<0x143, 0xc>(key); // row_bcast31 -> lane63 sorted top-8
      if (lane == 63) {
#pragma unroll
        for (int r = 0; r < KTOP; r++)
          cand_lds[(wid - 1) * KTOP + r] =
              (unsigned long long)__double_as_longlong(key[r]);
      }
    }
    __syncthreads(); // B1

    // per-step scalar: ivn = 1/max(||v||,1e-8)
    float ivn;
    {
      float tot = red_sh[0] + red_sh[1] + red_sh[2] + red_sh[3];
      ivn = 1.f / fmaxf(sqrtf(tot), 1e-8f);
    }

    float osr[EPT], osi[EPT]; // workers: normalized s (pre-update), for patch

    if (wid == 0) {
      // ---- merge 4 sorted lists (lanes 0-3, 2 DPP levels) ----
      double c[8];
#pragma unroll
      for (int r = 0; r < KTOP; r++) {
        unsigned long long v = (lane < 4) ? cand_lds[lane * KTOP + r] : 0ull;
        c[r] = __longlong_as_double((long long)v);
      }
      merge_level<0x111, 0xf>(c);
      merge_level<0x112, 0xf>(c); // lane 3 = global sorted top-8
      int top[KTOP];
#pragma unroll
      for (int r = 0; r < KTOP; r++)
        top[r] = ~__builtin_amdgcn_readlane(__double2loint(c[r]), 3);

      // ---- pair (ii,jj) for lane p, row-major triu order ----
      int pi = (lane < 28) ? lane : 27;
      int ii = 0, base = 0;
      if (pi >= 7)  { ii = 1; base = 7;  }
      if (pi >= 13) { ii = 2; base = 13; }
      if (pi >= 18) { ii = 3; base = 18; }
      if (pi >= 22) { ii = 4; base = 22; }
      if (pi >= 25) { ii = 5; base = 25; }
      if (pi >= 27) { ii = 6; base = 27; }
      int jj = ii + 1 + (pi - base);
      int gi = top[0];
      if (ii == 1) gi = top[1];
      if (ii == 2) gi = top[2];
      if (ii == 3) gi = top[3];
      if (ii == 4) gi = top[4];
      if (ii == 5) gi = top[5];
      if (ii == 6) gi = top[6];
      int gj = top[1];
      if (jj == 2) gj = top[2];
      if (jj == 3) gj = top[3];
      if (jj == 4) gj = top[4];
      if (jj == 5) gj = top[5];
      if (jj == 6) gj = top[6];
      if (jj == 7) gj = top[7];

      float4 c4i = sc4[gi], c4j = sc4[gj];
      float sri = c4i.y * ivn, sii2 = c4i.z * ivn;
      float srj = c4j.y * ivn, sij = c4j.z * ivn;
      float cri = c4i.x * sri, cii = c4i.x * sii2;
      float crj = c4j.x * srj, cij = c4j.x * sij;
      float score = cri * crj + cii * cij; // Re(c_i conj(c_j))
      bool valid = (lane < 28);
      bool pos = valid && (score > 0.f);
      unsigned long long posmask = __ballot(pos);
      int npos = __popcll(posmask);
      float pr = sri * srj - sii2 * sij;
      float pq = sri * sij + sii2 * srj;
      float ap = fmaxf(sqrtf(pr * pr + pq * pq), 1e-8f);
      float mr = (0.05f * pr) / ap, mi = (0.05f * pq) / ap;

      unsigned long long bmask = 0ull;
      if (npos > 0) {
        int nbind = (int)((float)npos * 0.15f);
        if (nbind < 1) nbind = 1;
        float val = pos ? score : -__builtin_inff();
        float th = 0.f;
        for (int k2 = 0; k2 < nbind; ++k2) {
          float mx = wave_max_f32(val);
          th = __int_as_float(rl63(__float_as_int(mx)));
          if (k2 + 1 < nbind) {
            unsigned long long em = __ballot(val == th);
            if (lane == (int)__builtin_ctzll(em)) val = -__builtin_inff();
          }
        }
        bool bind = valid && (score >= th);
        bmask = __ballot(bind);
      }
      // slot scan in pair order
      while (bmask) {
        int pp = (int)__builtin_ctzll(bmask);
        bmask &= bmask - 1;
        int pci = __builtin_amdgcn_readlane(gi, pp);
        int pcj = __builtin_amdgcn_readlane(gj, pp);
        int pmr = __builtin_amdgcn_readlane(__float_as_int(mr), pp);
        int pmi = __builtin_amdgcn_readlane(__float_as_int(mi), pp);
        bool isslot = (lane < MSLOT);
        bool match = isslot && (s_cnt > 0) &&
                     ((s_ti == pci && s_tj == pcj) ||
                      (s_ti == pcj && s_tj == pci));
        unsigned long long mm = __ballot(match);
        if (mm != 0ull) {
          if (lane == (int)__builtin_ctzll(mm)) s_cnt = 5; // refresh only
        } else {
          unsigned long long fm = __ballot(isslot && s_cnt <= 0);
          if (fm != 0ull && lane == (int)__builtin_ctzll(fm)) {
            s_ti = pci; s_tj = pcj;
            s_mre = __int_as_float(pmr); s_mim = __int_as_float(pmi);
            s_cnt = 5;
          }
        }
      }
      // decay + alive + scatter (dead slots add exact 0.0, like the ref)
      if (lane < MSLOT) {
        s_mre *= 0.9f; s_mim *= 0.9f; s_cnt -= 1;
        bool alive = (s_cnt > 0) &&
                     (sqrtf(s_mre * s_mre + s_mim * s_mim) > 1e-6f);
        if (!alive) { s_cnt = 0; s_mre = 0.f; s_mim = 0.f; }
        atomicAdd(&dxy[s_ti].x, 0.1f * s_mre);
        atomicAdd(&dxy[s_tj].x, 0.1f * s_mre);
        atomicAdd(&dxy[s_ti].y, 0.1f * s_mim);
        atomicAdd(&dxy[s_tj].y, 0.1f * s_mim);
      }
    } else {
      // ============ workers overlap wave0's serial section ============
      if (t + 1 < TSTEPS) {
        const float *xr = xb + (size_t)(t + 1) * DIM_;
#pragma unroll
        for (int j = 0; j < EPT; j++) hnext[j] = xr[wtid + NWORK * j];
      }
      if (t > 0) {
        float *op = out + ((size_t)b * TSTEPS + (t - 1)) * DIM_;
#pragma unroll
        for (int j = 0; j < EPT; j++) {
          float sr = vre[j] * ivn, si = vim[j] * ivn;
          op[wtid + NWORK * j] = sqrtf(sr * sr + si * si);
        }
      }
      // speculative update with delta = 0 (exact for untouched elements)
#pragma unroll
      for (int j = 0; j < EPT; j++) {
        float sri = vre[j] * ivn, sii2 = vim[j] * ivn;
        osr[j] = sri; osi[j] = sii2;
        float h = hcur[j];
        float car = h * sri, cai = h * sii2;
        bool res = (car > 1e-6f) && (fabsf(cai) < car);
        bool tor = (car < -1e-6f) || (fabsf(cai) >= fabsf(car));
        float m1 = (res || tor) ? 1.f : 0.f;
        float mt = tor ? 1.f : 0.f;
        float ur = eta * (car * m1 + mt * tbre_[j]);
        float ui = eta * (cai * m1 + mt * tbim_[j]);
        vre[j] = sri + ur; vim[j] = sii2 + ui;
      }
    }
    __syncthreads(); // B2

    // ============ [C] workers: sparse patch + norm ============
    if (wid > 0) {
      float2 dd[EPT];
#pragma unroll
      for (int j = 0; j < EPT; j++) dd[j] = dxy[wtid + NWORK * j];
      float acc2 = 0.f;
#pragma unroll
      for (int j = 0; j < EPT; j++) {
        if (dd[j].x != 0.f || dd[j].y != 0.f) {
          float ar = osr[j] + dd[j].x, ai = osi[j] + dd[j].y;
          float h = hcur[j];
          float car = h * ar, cai = h * ai;
          bool res = (car > 1e-6f) && (fabsf(cai) < car);
          bool tor = (car < -1e-6f) || (fabsf(cai) >= fabsf(car));
          float m1 = (res || tor) ? 1.f : 0.f;
          float mt = tor ? 1.f : 0.f;
          float ur = eta * (car * m1 + mt * tbre_[j]);
          float ui = eta * (cai * m1 + mt * tbim_[j]);
          vre[j] = osr[j] + ur; vim[j] = osi[j] + ui;
        }
        acc2 += vre[j] * vre[j] + vim[j] * vim[j];
      }
      float ws = wave_sum_f32(acc2);
      if (lane == 63) red_sh[wid - 1] = ws;
#pragma unroll
      for (int j = 0; j < EPT; j++) hcur[j] = hnext[j];
    }
  }

  // epilogue: final output row
  __syncthreads();
  if (wid > 0) {
    float tot = red_sh[0] + red_sh[1] + red_sh[2] + red_sh[3];
    float ivnF = 1.f / fmaxf(sqrtf(tot), 1e-8f);
    float *op = out + ((size_t)b * TSTEPS + (TSTEPS - 1)) * DIM_;
#pragma unroll
    for (int j = 0; j < EPT; j++) {
      float sr = vre[j] * ivnF, si = vim[j] * ivnF;
      op[wtid + NWORK * j] = sqrtf(sr * sr + si * si);
    }
  }
}

extern "C" void kernel_launch(void *const *d_in, const int *in_sizes, int n_in,
                              void *d_out, int out_size, void *d_ws,
                              size_t ws_size, hipStream_t stream) {
  const float *x = (const float *)d_in[0];
  const float *tre = (const float *)d_in[1];
  const float *tim = (const float *)d_in[2];
  const float *eta = (const float *)d_in[3];
  const float *tbre = (const float *)d_in[4];
  const float *tbim = (const float *)d_in[5];
  float *out = (float *)d_out;
  me_fused<<<NB, NTHREADS, 0, stream>>>(x, tre, tim, eta, tbre, tbim, out);
}